// Round 4
// baseline (74.616 us; speedup 1.0000x reference)
//
#include <hip/hip_runtime.h>

typedef __attribute__((ext_vector_type(4))) float f32x4;
typedef __attribute__((ext_vector_type(8))) short bf16x8;
typedef unsigned short u16;
typedef unsigned int u32;

constexpr int NN = 4096;   // H*W

__device__ __forceinline__ u16 f2bf(float f){
  u32 u = __builtin_bit_cast(u32, f);
  u += 0x7FFFu + ((u >> 16) & 1u);          // round-to-nearest-even
  return (u16)(u >> 16);
}
__device__ __forceinline__ u32 cvtpk(float lo, float hi){
  u32 r;
  asm("v_cvt_pk_bf16_f32 %0, %1, %2" : "=v"(r) : "v"(lo), "v"(hi));
  return r;
}
__device__ __forceinline__ void async16(void* lds, const void* g){
  __builtin_amdgcn_global_load_lds((const __attribute__((address_space(1))) void*)g,
                                   (__attribute__((address_space(3))) void*)lds,
                                   16, 0, 0);
}

// ---------------------------------------------------------------------------
// proj v4: single x-pass. grid = 256 (4 batches x 64 n-chunks), 4 waves.
// Each thread owns one n; wave w computes o in [w*16, w*16+16) for all 3 mats.
// theta gets *log2e folded in. theta_t/phi_t: [b][n][o] bf16; g: [b][o][n].
// ---------------------------------------------------------------------------
__global__ __launch_bounds__(256) void proj_kernel(
    const float* __restrict__ x,
    const float* __restrict__ wth, const float* __restrict__ bth,
    const float* __restrict__ wph, const float* __restrict__ bph,
    const float* __restrict__ wg,  const float* __restrict__ bg,
    u16* __restrict__ theta_t, u16* __restrict__ phi_t, u16* __restrict__ gbuf)
{
  const int b = blockIdx.x >> 6;
  const int n = (blockIdx.x & 63) * 64 + (threadIdx.x & 63);
  const int w = __builtin_amdgcn_readfirstlane((int)threadIdx.x >> 6);

  const float* xb = x + ((size_t)b * 64) * NN + n;
  float xr[64];
#pragma unroll
  for (int c = 0; c < 64; ++c) xr[c] = xb[(size_t)c * NN];

  for (int mat = 0; mat < 3; ++mat){
    const float* W  = (mat == 0) ? wth : (mat == 1) ? wph : wg;
    const float* Bb = (mat == 0) ? bth : (mat == 1) ? bph : bg;
    float acc[16];
#pragma unroll
    for (int oo = 0; oo < 16; ++oo) acc[oo] = Bb[w * 16 + oo];
    for (int c = 0; c < 64; ++c)
#pragma unroll
      for (int oo = 0; oo < 16; ++oo)
        acc[oo] += W[(w * 16 + oo) * 64 + c] * xr[c];

    if (mat == 0){
#pragma unroll
      for (int oo = 0; oo < 16; ++oo) acc[oo] *= 1.44269504088896340736f;
    }
    if (mat < 2){
      u32 pk[8];
#pragma unroll
      for (int h = 0; h < 8; ++h) pk[h] = cvtpk(acc[2 * h], acc[2 * h + 1]);
      u16* base = (mat == 0) ? theta_t : phi_t;
      u32* dst = (u32*)(base + ((size_t)(b * NN + n)) * 64 + w * 16);
      ((uint4*)dst)[0] = ((const uint4*)pk)[0];
      ((uint4*)dst)[1] = ((const uint4*)pk)[1];
    } else {
#pragma unroll
      for (int oo = 0; oo < 16; ++oo)
        gbuf[((size_t)(b * 64 + w * 16 + oo)) * NN + n] = f2bf(acc[oo]);
    }
  }
}

// ---------------------------------------------------------------------------
// attn v4: BM=128 (8 waves x 16 rows), m-split flash, fixed-base softmax,
// permlane P-redistribution, XCD-aware L2 blocking.
// grid = S*128 blocks (512 threads); logical id via bijective swizzle.
// ---------------------------------------------------------------------------
__global__ __launch_bounds__(512) void attn_kernel(
    const u16* __restrict__ theta_t, const u16* __restrict__ phi_t,
    const u16* __restrict__ gbuf,
    u16* __restrict__ y_part, float* __restrict__ l_part, int tpb)
{
  __shared__ u16 phi_sm[2][64 * 64];  // [m_loc][o], XOR-swizzled
  __shared__ u16 g_sm[2][64 * 64];    // [o][m_loc], XOR-swizzled

  // bijective XCD swizzle (grid % 8 == 0): XCD j%8 gets a contiguous lb-run
  const int j   = blockIdx.x;
  const int cpx = gridDim.x >> 3;
  const int lb  = (j & 7) * cpx + (j >> 3);

  const int ms  = lb >> 7;            // m-split index (0..S-1)
  const int bt  = lb & 127;           // 0..127: batch*32 + chunk
  const int b   = bt >> 5;
  const int n0  = (bt & 31) * 128;
  const int w   = __builtin_amdgcn_readfirstlane((int)threadIdx.x >> 6); // 0..7
  const int l   = threadIdx.x & 63;
  const int q   = l & 15;
  const int g   = l >> 4;
  const int swz = (q & 7) << 4;

  const u16* thb = theta_t + (size_t)b * NN * 64;
  const u16* phb = phi_t   + (size_t)b * NN * 64;
  const u16* gbb = gbuf    + (size_t)b * 64 * NN;

  bf16x8 tf[2];
#pragma unroll
  for (int ks = 0; ks < 2; ++ks)
    tf[ks] = *(const bf16x8*)(thb + (size_t)(n0 + w * 16 + q) * 64 + ks * 32 + g * 8);

  const int r8 = l >> 3;
  const int c8 = l & 7;
  // wave w stages 1KB chunk w of phi and of g (8 rows each)
  auto STAGE = [&](int buf, int mt){
    const int row = w * 8 + r8;
    const int cs  = c8 ^ r8;             // pre-swizzled source (rule #21)
    async16(&phi_sm[buf][w * 512], phb + (size_t)(mt * 64 + row) * 64 + cs * 8);
    async16(&g_sm[buf][w * 512],   gbb + (size_t)row * NN + mt * 64 + cs * 8);
  };

  f32x4 yacc[4];
#pragma unroll
  for (int os = 0; os < 4; ++os) yacc[os] = (f32x4){0.f, 0.f, 0.f, 0.f};
  float lacc = 0.f;

  const int m0 = ms * tpb;
  STAGE(0, m0);

  for (int it = 0; it < tpb; ++it){
    const int mt  = m0 + it;
    const int cur = it & 1;
    if (it < tpb - 1){
      STAGE(cur ^ 1, mt + 1);
      asm volatile("s_waitcnt vmcnt(2)" ::: "memory");
    } else {
      asm volatile("s_waitcnt vmcnt(0)" ::: "memory");
    }
    __builtin_amdgcn_s_barrier();

    const char* phiB = (const char*)&phi_sm[cur][0];
    const char* gB   = (const char*)&g_sm[cur][0];

    // swapped QK^T: lane (q,g) holds P[n=q][m = s*16+g*4+r]
    __builtin_amdgcn_s_setprio(1);
    f32x4 d[4];
#pragma unroll
    for (int s = 0; s < 4; ++s){
      f32x4 acc = (f32x4){0.f, 0.f, 0.f, 0.f};
#pragma unroll
      for (int ks = 0; ks < 2; ++ks){
        const int off = (((s * 16 + q) * 128) + ks * 64 + g * 16) ^ swz;
        const bf16x8 af = *(const bf16x8*)(phiB + off);
        acc = __builtin_amdgcn_mfma_f32_16x16x32_bf16(af, tf[ks], acc, 0, 0, 0);
      }
      d[s] = acc;
    }
    __builtin_amdgcn_s_setprio(0);

    // fixed-base softmax: p = exp2(score) directly; pack to bf16 pairs
    u32 e[4][2];
#pragma unroll
    for (int s = 0; s < 4; ++s){
      const float p0 = exp2f(d[s][0]), p1 = exp2f(d[s][1]);
      const float p2 = exp2f(d[s][2]), p3 = exp2f(d[s][3]);
      lacc += (p0 + p1) + (p2 + p3);
      e[s][0] = cvtpk(p0, p1);
      e[s][1] = cvtpk(p2, p3);
    }

    // PV with in-register P redistribution via permlane swaps
    __builtin_amdgcn_s_setprio(1);
#pragma unroll
    for (int ks2 = 0; ks2 < 2; ++ks2){
      u32 a0 = e[2 * ks2][0], b0 = e[2 * ks2 + 1][0];
      u32 a1 = e[2 * ks2][1], b1 = e[2 * ks2 + 1][1];
      asm("v_permlane32_swap_b32 %0, %1" : "+v"(a0), "+v"(b0));
      asm("v_permlane16_swap_b32 %0, %1" : "+v"(a0), "+v"(b0));
      asm("v_permlane32_swap_b32 %0, %1" : "+v"(a1), "+v"(b1));
      asm("v_permlane16_swap_b32 %0, %1" : "+v"(a1), "+v"(b1));
      union { u32 u[4]; bf16x8 v; } pw;
      pw.u[0] = a0; pw.u[1] = a1; pw.u[2] = b0; pw.u[3] = b1;
#pragma unroll
      for (int os = 0; os < 4; ++os){
        const int off = (((os * 16 + q) * 128) + ks2 * 64 + g * 16) ^ swz;
        const bf16x8 gf = *(const bf16x8*)(gB + off);
        yacc[os] = __builtin_amdgcn_mfma_f32_16x16x32_bf16(pw.v, gf, yacc[os], 0, 0, 0);
      }
    }
    __builtin_amdgcn_s_setprio(0);
    __builtin_amdgcn_s_barrier();
  }

  // deferred l reduction (reduce over g)
  lacc += __shfl_xor(lacc, 16);
  lacc += __shfl_xor(lacc, 32);

  // partials: y_part[lb][n_loc(128)][o(64)] bf16, l_part[lb][n_loc(128)] f32
  u16* yp = y_part + (size_t)lb * (128 * 64);
#pragma unroll
  for (int os = 0; os < 4; ++os)
#pragma unroll
    for (int r = 0; r < 4; ++r)
      yp[(size_t)(w * 16 + g * 4 + r) * 64 + os * 16 + q] = f2bf(yacc[os][r]);

  if (g == 0)
    l_part[(size_t)lb * 128 + w * 16 + q] = lacc;
}

// ---------------------------------------------------------------------------
// combine v4: 512 blocks x 32 rows. Sum S bf16 partials, normalize,
// w_out GEMM + bias/ReLU/BN + residual.
// ---------------------------------------------------------------------------
__global__ __launch_bounds__(256) void combine_kernel(
    const u16* __restrict__ y_part, const float* __restrict__ l_part,
    const float* __restrict__ x,
    const float* __restrict__ w_out, const float* __restrict__ b_out,
    const float* __restrict__ bn_gamma, const float* __restrict__ bn_beta,
    float* __restrict__ out, int S)
{
  __shared__ u16 y_sm[32 * 64];       // [row][o] bf16, swizzled
  __shared__ float inv_sm[32];

  const int cb      = blockIdx.x;           // 0..511
  const int b       = cb >> 7;
  const int nin     = (cb & 127) * 32;      // within-batch row base
  const int bt      = b * 32 + (nin >> 7);  // attn block id (0..127)
  const int rowbase = nin & 127;            // row base within attn block
  const int t       = threadIdx.x;
  const int row     = t >> 3;               // 0..31
  const int ch      = t & 7;                // 16B chunk (8 bf16)

  float s[8] = {0.f,0.f,0.f,0.f,0.f,0.f,0.f,0.f};
  for (int ms = 0; ms < S; ++ms){
    const u16* src = y_part + ((size_t)(ms * 128 + bt)) * (128 * 64)
                   + (size_t)(rowbase + row) * 64 + ch * 8;
    const uint4 v = *(const uint4*)src;
    const u32 ww[4] = {v.x, v.y, v.z, v.w};
#pragma unroll
    for (int i = 0; i < 4; ++i){
      s[2 * i]     += __builtin_bit_cast(float, ww[i] << 16);
      s[2 * i + 1] += __builtin_bit_cast(float, ww[i] & 0xFFFF0000u);
    }
  }
  if (t < 32){
    float ls = 0.f;
    for (int ms = 0; ms < S; ++ms)
      ls += l_part[((size_t)(ms * 128 + bt)) * 128 + rowbase + t];
    inv_sm[t] = 1.0f / ls;
  }
  __syncthreads();

  {
    const float inv = inv_sm[row];
    uint4 pk;
    pk.x = cvtpk(s[0] * inv, s[1] * inv);
    pk.y = cvtpk(s[2] * inv, s[3] * inv);
    pk.z = cvtpk(s[4] * inv, s[5] * inv);
    pk.w = cvtpk(s[6] * inv, s[7] * inv);
    *(uint4*)((char*)y_sm + ((row * 128 + ch * 16) ^ ((row & 7) << 4))) = pk;
  }
  __syncthreads();

  // epilogue GEMM: z[c][n] = sum_o w_out[c][o] * y[n][o]
  const int w   = __builtin_amdgcn_readfirstlane(t >> 6);
  const int l   = t & 63;
  const int q   = l & 15;
  const int gg  = l >> 4;
  const int swz = (q & 7) << 4;

  bf16x8 wf[2];
#pragma unroll
  for (int ks = 0; ks < 2; ++ks){
    bf16x8 v;
#pragma unroll
    for (int j = 0; j < 8; ++j)
      v[j] = (short)f2bf(w_out[(w * 16 + q) * 64 + ks * 32 + gg * 8 + j]);
    wf[ks] = v;
  }
  f32x4 zacc[2];
  zacc[0] = (f32x4){0.f, 0.f, 0.f, 0.f};
  zacc[1] = (f32x4){0.f, 0.f, 0.f, 0.f};
#pragma unroll
  for (int ks = 0; ks < 2; ++ks)
#pragma unroll
    for (int ns = 0; ns < 2; ++ns){
      const int off = (((ns * 16 + q) * 128) + ks * 64 + gg * 16) ^ swz;
      const bf16x8 yf = *(const bf16x8*)((const char*)y_sm + off);
      zacc[ns] = __builtin_amdgcn_mfma_f32_16x16x32_bf16(wf[ks], yf, zacc[ns], 0, 0, 0);
    }

  float bo[4], sc_[4], bb_[4];
#pragma unroll
  for (int r = 0; r < 4; ++r){
    const int c = w * 16 + gg * 4 + r;
    bo[r]  = b_out[c];
    sc_[r] = bn_gamma[c] * 0.99999500003749969f;  // 1/sqrt(1+1e-5)
    bb_[r] = bn_beta[c];
  }
#pragma unroll
  for (int ns = 0; ns < 2; ++ns)
#pragma unroll
    for (int r = 0; r < 4; ++r){
      const int c  = w * 16 + gg * 4 + r;
      const int ng = nin + ns * 16 + q;
      const size_t idx = ((size_t)(b * 64 + c)) * NN + ng;
      float z = zacc[ns][r] + bo[r];
      z = fmaxf(z, 0.0f);
      z = z * sc_[r] + bb_[r];
      out[idx] = x[idx] + z;
    }
}

// ---------------------------------------------------------------------------
extern "C" void kernel_launch(void* const* d_in, const int* in_sizes, int n_in,
                              void* d_out, int out_size, void* d_ws, size_t ws_size,
                              hipStream_t stream)
{
  (void)in_sizes; (void)n_in; (void)out_size;
  const float* x        = (const float*)d_in[0];
  const float* w_theta  = (const float*)d_in[1];
  const float* b_theta  = (const float*)d_in[2];
  const float* w_phi    = (const float*)d_in[3];
  const float* b_phi    = (const float*)d_in[4];
  const float* w_g      = (const float*)d_in[5];
  const float* b_g      = (const float*)d_in[6];
  const float* w_out    = (const float*)d_in[7];
  const float* b_out    = (const float*)d_in[8];
  const float* bn_gamma = (const float*)d_in[9];
  const float* bn_beta  = (const float*)d_in[10];
  float* out = (float*)d_out;

  u16* theta_t = (u16*)d_ws;                       // 2 MB
  u16* phi_t   = theta_t + (size_t)4 * NN * 64;    // 2 MB
  u16* gbuf    = phi_t   + (size_t)4 * NN * 64;    // 2 MB
  char* after  = (char*)(gbuf + (size_t)4 * NN * 64);
  const size_t used = (size_t)(after - (char*)d_ws);
  const size_t perS = (size_t)128 * 128 * 64 * 2 + (size_t)128 * 128 * 4; // ~2.06 MB

  int S = 1;
  if (ws_size >= used + 4 * perS) S = 4;
  else if (ws_size >= used + 2 * perS) S = 2;
  u16*   y_part = (u16*)after;
  float* l_part = (float*)(y_part + (size_t)S * 128 * 128 * 64);
  const int tpb = 64 / S;

  proj_kernel<<<256, 256, 0, stream>>>(x, w_theta, b_theta, w_phi, b_phi,
                                       w_g, b_g, theta_t, phi_t, gbuf);
  attn_kernel<<<128 * S, 512, 0, stream>>>(theta_t, phi_t, gbuf, y_part, l_part, tpb);
  combine_kernel<<<512, 256, 0, stream>>>(y_part, l_part, x, w_out, b_out,
                                          bn_gamma, bn_beta, out, S);
}

// Round 5
// 71.476 us; speedup vs baseline: 1.0439x; 1.0439x over previous
//
#include <hip/hip_runtime.h>

typedef __attribute__((ext_vector_type(4))) float f32x4;
typedef __attribute__((ext_vector_type(8))) short bf16x8;
typedef unsigned short u16;
typedef unsigned int u32;

constexpr int NN = 4096;   // H*W

__device__ __forceinline__ u16 f2bf(float f){
  u32 u = __builtin_bit_cast(u32, f);
  u += 0x7FFFu + ((u >> 16) & 1u);          // round-to-nearest-even
  return (u16)(u >> 16);
}
__device__ __forceinline__ u32 cvtpk(float lo, float hi){
  u32 r;
  asm("v_cvt_pk_bf16_f32 %0, %1, %2" : "=v"(r) : "v"(lo), "v"(hi));
  return r;
}
__device__ __forceinline__ float fexp2(float x){
  float r;
  asm("v_exp_f32 %0, %1" : "=v"(r) : "v"(x));   // raw transcendental, no libm edge code
  return r;
}
__device__ __forceinline__ void async16(void* lds, const void* g){
  __builtin_amdgcn_global_load_lds((const __attribute__((address_space(1))) void*)g,
                                   (__attribute__((address_space(3))) void*)lds,
                                   16, 0, 0);
}

// ---------------------------------------------------------------------------
// proj v5: weights staged in LDS (48 KB); xr fully register-resident.
// grid = 256 (4 batches x 64 n-chunks), 4 waves; wave w owns o in [16w,16w+16).
// theta gets *log2e folded in. theta_t/phi_t: [b][n][o] bf16; g: [b][o][n].
// ---------------------------------------------------------------------------
__global__ __launch_bounds__(256) void proj_kernel(
    const float* __restrict__ x,
    const float* __restrict__ wth, const float* __restrict__ bth,
    const float* __restrict__ wph, const float* __restrict__ bph,
    const float* __restrict__ wg,  const float* __restrict__ bg,
    u16* __restrict__ theta_t, u16* __restrict__ phi_t, u16* __restrict__ gbuf)
{
  __shared__ float Wsm[3 * 64 * 64];   // 48 KB
  __shared__ float Bsm[3 * 64];

  const int t = threadIdx.x;
  // stage weights (each mat = 4096 floats = 1024 float4; 256 threads x 4)
#pragma unroll
  for (int i = 0; i < 4; ++i){
    ((float4*)Wsm)[i * 256 + t]            = ((const float4*)wth)[i * 256 + t];
    ((float4*)(Wsm + 4096))[i * 256 + t]   = ((const float4*)wph)[i * 256 + t];
    ((float4*)(Wsm + 8192))[i * 256 + t]   = ((const float4*)wg)[i * 256 + t];
  }
  if (t < 64){ Bsm[t] = bth[t]; Bsm[64 + t] = bph[t]; Bsm[128 + t] = bg[t]; }

  const int b = blockIdx.x >> 6;
  const int n = (blockIdx.x & 63) * 64 + (t & 63);
  const int w = __builtin_amdgcn_readfirstlane(t >> 6);

  const float* xb = x + ((size_t)b * 64) * NN + n;
  float xr[64];
#pragma unroll
  for (int c = 0; c < 64; ++c) xr[c] = xb[(size_t)c * NN];

  __syncthreads();

  for (int mat = 0; mat < 3; ++mat){
    const float* Wm = Wsm + mat * 4096 + (w * 16) * 64;
    float acc[16];
#pragma unroll
    for (int oo = 0; oo < 16; ++oo) acc[oo] = Bsm[mat * 64 + w * 16 + oo];
#pragma unroll
    for (int c4 = 0; c4 < 16; ++c4)
#pragma unroll
      for (int oo = 0; oo < 16; ++oo){
        const float4 wv = *(const float4*)&Wm[oo * 64 + c4 * 4];  // wave-broadcast
        acc[oo] = fmaf(wv.x, xr[4 * c4],     acc[oo]);
        acc[oo] = fmaf(wv.y, xr[4 * c4 + 1], acc[oo]);
        acc[oo] = fmaf(wv.z, xr[4 * c4 + 2], acc[oo]);
        acc[oo] = fmaf(wv.w, xr[4 * c4 + 3], acc[oo]);
      }

    if (mat == 0){
#pragma unroll
      for (int oo = 0; oo < 16; ++oo) acc[oo] *= 1.44269504088896340736f;
    }
    if (mat < 2){
      u32 pk[8];
#pragma unroll
      for (int h = 0; h < 8; ++h) pk[h] = cvtpk(acc[2 * h], acc[2 * h + 1]);
      u16* base = (mat == 0) ? theta_t : phi_t;
      u32* dst = (u32*)(base + ((size_t)(b * NN + n)) * 64 + w * 16);
      ((uint4*)dst)[0] = ((const uint4*)pk)[0];
      ((uint4*)dst)[1] = ((const uint4*)pk)[1];
    } else {
#pragma unroll
      for (int oo = 0; oo < 16; ++oo)
        gbuf[((size_t)(b * 64 + w * 16 + oo)) * NN + n] = f2bf(acc[oo]);
    }
  }
}

// ---------------------------------------------------------------------------
// attn v5: BM=128 (8 waves x 16 rows), m-split flash (S=8 -> 4 blocks/CU),
// fixed-base softmax w/ raw v_exp_f32, permlane P-redistribution,
// XCD-aware bijective swizzle (XCD k serves m-split k: ~512KB L2 set).
// ---------------------------------------------------------------------------
__global__ __launch_bounds__(512) void attn_kernel(
    const u16* __restrict__ theta_t, const u16* __restrict__ phi_t,
    const u16* __restrict__ gbuf,
    u16* __restrict__ y_part, float* __restrict__ l_part, int tpb)
{
  __shared__ u16 phi_sm[2][64 * 64];  // [m_loc][o], XOR-swizzled
  __shared__ u16 g_sm[2][64 * 64];    // [o][m_loc], XOR-swizzled

  const int j   = blockIdx.x;
  const int cpx = gridDim.x >> 3;
  const int lb  = (j & 7) * cpx + (j >> 3);   // bijective (grid % 8 == 0)

  const int ms  = lb >> 7;            // m-split index (0..S-1)
  const int bt  = lb & 127;           // batch*32 + n-chunk
  const int b   = bt >> 5;
  const int n0  = (bt & 31) * 128;
  const int w   = __builtin_amdgcn_readfirstlane((int)threadIdx.x >> 6); // 0..7
  const int l   = threadIdx.x & 63;
  const int q   = l & 15;
  const int g   = l >> 4;
  const int swz = (q & 7) << 4;

  const u16* thb = theta_t + (size_t)b * NN * 64;
  const u16* phb = phi_t   + (size_t)b * NN * 64;
  const u16* gbb = gbuf    + (size_t)b * 64 * NN;

  bf16x8 tf[2];
#pragma unroll
  for (int ks = 0; ks < 2; ++ks)
    tf[ks] = *(const bf16x8*)(thb + (size_t)(n0 + w * 16 + q) * 64 + ks * 32 + g * 8);

  const int r8 = l >> 3;
  const int c8 = l & 7;
  auto STAGE = [&](int buf, int mt){
    const int row = w * 8 + r8;
    const int cs  = c8 ^ r8;             // pre-swizzled source (rule #21)
    async16(&phi_sm[buf][w * 512], phb + (size_t)(mt * 64 + row) * 64 + cs * 8);
    async16(&g_sm[buf][w * 512],   gbb + (size_t)row * NN + mt * 64 + cs * 8);
  };

  f32x4 yacc[4];
#pragma unroll
  for (int os = 0; os < 4; ++os) yacc[os] = (f32x4){0.f, 0.f, 0.f, 0.f};
  float lacc = 0.f;

  const int m0 = ms * tpb;
  STAGE(0, m0);

  for (int it = 0; it < tpb; ++it){
    const int mt  = m0 + it;
    const int cur = it & 1;
    if (it < tpb - 1){
      STAGE(cur ^ 1, mt + 1);
      asm volatile("s_waitcnt vmcnt(2)" ::: "memory");
    } else {
      asm volatile("s_waitcnt vmcnt(0)" ::: "memory");
    }
    __builtin_amdgcn_s_barrier();

    const char* phiB = (const char*)&phi_sm[cur][0];
    const char* gB   = (const char*)&g_sm[cur][0];

    // swapped QK^T: lane (q,g) holds P[n=q][m = s*16+g*4+r]
    __builtin_amdgcn_s_setprio(1);
    f32x4 d[4];
#pragma unroll
    for (int s = 0; s < 4; ++s){
      f32x4 acc = (f32x4){0.f, 0.f, 0.f, 0.f};
#pragma unroll
      for (int ks = 0; ks < 2; ++ks){
        const int off = (((s * 16 + q) * 128) + ks * 64 + g * 16) ^ swz;
        const bf16x8 af = *(const bf16x8*)(phiB + off);
        acc = __builtin_amdgcn_mfma_f32_16x16x32_bf16(af, tf[ks], acc, 0, 0, 0);
      }
      d[s] = acc;
    }
    __builtin_amdgcn_s_setprio(0);

    // fixed-base softmax: p = exp2(score) directly (raw v_exp_f32)
    u32 e[4][2];
#pragma unroll
    for (int s = 0; s < 4; ++s){
      const float p0 = fexp2(d[s][0]), p1 = fexp2(d[s][1]);
      const float p2 = fexp2(d[s][2]), p3 = fexp2(d[s][3]);
      lacc += (p0 + p1) + (p2 + p3);
      e[s][0] = cvtpk(p0, p1);
      e[s][1] = cvtpk(p2, p3);
    }

    // PV with in-register P redistribution via permlane swaps
    __builtin_amdgcn_s_setprio(1);
#pragma unroll
    for (int ks2 = 0; ks2 < 2; ++ks2){
      u32 a0 = e[2 * ks2][0], b0 = e[2 * ks2 + 1][0];
      u32 a1 = e[2 * ks2][1], b1 = e[2 * ks2 + 1][1];
      asm("v_permlane32_swap_b32 %0, %1" : "+v"(a0), "+v"(b0));
      asm("v_permlane16_swap_b32 %0, %1" : "+v"(a0), "+v"(b0));
      asm("v_permlane32_swap_b32 %0, %1" : "+v"(a1), "+v"(b1));
      asm("v_permlane16_swap_b32 %0, %1" : "+v"(a1), "+v"(b1));
      union { u32 u[4]; bf16x8 v; } pw;
      pw.u[0] = a0; pw.u[1] = a1; pw.u[2] = b0; pw.u[3] = b1;
#pragma unroll
      for (int os = 0; os < 4; ++os){
        const int off = (((os * 16 + q) * 128) + ks2 * 64 + g * 16) ^ swz;
        const bf16x8 gf = *(const bf16x8*)(gB + off);
        yacc[os] = __builtin_amdgcn_mfma_f32_16x16x32_bf16(pw.v, gf, yacc[os], 0, 0, 0);
      }
    }
    __builtin_amdgcn_s_setprio(0);
    __builtin_amdgcn_s_barrier();
  }

  // deferred l reduction (reduce over g)
  lacc += __shfl_xor(lacc, 16);
  lacc += __shfl_xor(lacc, 32);

  // partials: y_part[lb][n_loc(128)][o(64)] bf16, l_part[lb][n_loc(128)] f32
  u16* yp = y_part + (size_t)lb * (128 * 64);
#pragma unroll
  for (int os = 0; os < 4; ++os)
#pragma unroll
    for (int r = 0; r < 4; ++r)
      yp[(size_t)(w * 16 + g * 4 + r) * 64 + os * 16 + q] = f2bf(yacc[os][r]);

  if (g == 0)
    l_part[(size_t)lb * 128 + w * 16 + q] = lacc;
}

// ---------------------------------------------------------------------------
// combine v5: 512 blocks x 32 rows. Sum S bf16 partials, normalize,
// w_out GEMM + bias/ReLU/BN + residual.
// ---------------------------------------------------------------------------
__global__ __launch_bounds__(256) void combine_kernel(
    const u16* __restrict__ y_part, const float* __restrict__ l_part,
    const float* __restrict__ x,
    const float* __restrict__ w_out, const float* __restrict__ b_out,
    const float* __restrict__ bn_gamma, const float* __restrict__ bn_beta,
    float* __restrict__ out, int S)
{
  __shared__ u16 y_sm[32 * 64];       // [row][o] bf16, swizzled
  __shared__ float inv_sm[32];

  const int cb      = blockIdx.x;           // 0..511
  const int b       = cb >> 7;
  const int nin     = (cb & 127) * 32;      // within-batch row base
  const int bt      = b * 32 + (nin >> 7);  // attn block id (0..127)
  const int rowbase = nin & 127;            // row base within attn block
  const int t       = threadIdx.x;
  const int row     = t >> 3;               // 0..31
  const int ch      = t & 7;                // 16B chunk (8 bf16)

  float s[8] = {0.f,0.f,0.f,0.f,0.f,0.f,0.f,0.f};
  for (int ms = 0; ms < S; ++ms){
    const u16* src = y_part + ((size_t)(ms * 128 + bt)) * (128 * 64)
                   + (size_t)(rowbase + row) * 64 + ch * 8;
    const uint4 v = *(const uint4*)src;
    const u32 ww[4] = {v.x, v.y, v.z, v.w};
#pragma unroll
    for (int i = 0; i < 4; ++i){
      s[2 * i]     += __builtin_bit_cast(float, ww[i] << 16);
      s[2 * i + 1] += __builtin_bit_cast(float, ww[i] & 0xFFFF0000u);
    }
  }
  if (t < 32){
    float ls = 0.f;
    for (int ms = 0; ms < S; ++ms)
      ls += l_part[((size_t)(ms * 128 + bt)) * 128 + rowbase + t];
    inv_sm[t] = 1.0f / ls;
  }
  __syncthreads();

  {
    const float inv = inv_sm[row];
    uint4 pk;
    pk.x = cvtpk(s[0] * inv, s[1] * inv);
    pk.y = cvtpk(s[2] * inv, s[3] * inv);
    pk.z = cvtpk(s[4] * inv, s[5] * inv);
    pk.w = cvtpk(s[6] * inv, s[7] * inv);
    *(uint4*)((char*)y_sm + ((row * 128 + ch * 16) ^ ((row & 7) << 4))) = pk;
  }
  __syncthreads();

  // epilogue GEMM: z[c][n] = sum_o w_out[c][o] * y[n][o]
  const int w   = __builtin_amdgcn_readfirstlane(t >> 6);
  const int l   = t & 63;
  const int q   = l & 15;
  const int gg  = l >> 4;
  const int swz = (q & 7) << 4;

  bf16x8 wf[2];
#pragma unroll
  for (int ks = 0; ks < 2; ++ks){
    bf16x8 v;
#pragma unroll
    for (int jj = 0; jj < 8; ++jj)
      v[jj] = (short)f2bf(w_out[(w * 16 + q) * 64 + ks * 32 + gg * 8 + jj]);
    wf[ks] = v;
  }
  f32x4 zacc[2];
  zacc[0] = (f32x4){0.f, 0.f, 0.f, 0.f};
  zacc[1] = (f32x4){0.f, 0.f, 0.f, 0.f};
#pragma unroll
  for (int ks = 0; ks < 2; ++ks)
#pragma unroll
    for (int ns = 0; ns < 2; ++ns){
      const int off = (((ns * 16 + q) * 128) + ks * 64 + gg * 16) ^ swz;
      const bf16x8 yf = *(const bf16x8*)((const char*)y_sm + off);
      zacc[ns] = __builtin_amdgcn_mfma_f32_16x16x32_bf16(wf[ks], yf, zacc[ns], 0, 0, 0);
    }

  float bo[4], sc_[4], bb_[4];
#pragma unroll
  for (int r = 0; r < 4; ++r){
    const int c = w * 16 + gg * 4 + r;
    bo[r]  = b_out[c];
    sc_[r] = bn_gamma[c] * 0.99999500003749969f;  // 1/sqrt(1+1e-5)
    bb_[r] = bn_beta[c];
  }
#pragma unroll
  for (int ns = 0; ns < 2; ++ns)
#pragma unroll
    for (int r = 0; r < 4; ++r){
      const int c  = w * 16 + gg * 4 + r;
      const int ng = nin + ns * 16 + q;
      const size_t idx = ((size_t)(b * 64 + c)) * NN + ng;
      float z = zacc[ns][r] + bo[r];
      z = fmaxf(z, 0.0f);
      z = z * sc_[r] + bb_[r];
      out[idx] = x[idx] + z;
    }
}

// ---------------------------------------------------------------------------
extern "C" void kernel_launch(void* const* d_in, const int* in_sizes, int n_in,
                              void* d_out, int out_size, void* d_ws, size_t ws_size,
                              hipStream_t stream)
{
  (void)in_sizes; (void)n_in; (void)out_size;
  const float* x        = (const float*)d_in[0];
  const float* w_theta  = (const float*)d_in[1];
  const float* b_theta  = (const float*)d_in[2];
  const float* w_phi    = (const float*)d_in[3];
  const float* b_phi    = (const float*)d_in[4];
  const float* w_g      = (const float*)d_in[5];
  const float* b_g      = (const float*)d_in[6];
  const float* w_out    = (const float*)d_in[7];
  const float* b_out    = (const float*)d_in[8];
  const float* bn_gamma = (const float*)d_in[9];
  const float* bn_beta  = (const float*)d_in[10];
  float* out = (float*)d_out;

  u16* theta_t = (u16*)d_ws;                       // 2 MB
  u16* phi_t   = theta_t + (size_t)4 * NN * 64;    // 2 MB
  u16* gbuf    = phi_t   + (size_t)4 * NN * 64;    // 2 MB
  char* after  = (char*)(gbuf + (size_t)4 * NN * 64);
  const size_t used = (size_t)(after - (char*)d_ws);
  const size_t perS = (size_t)128 * 128 * 64 * 2 + (size_t)128 * 128 * 4; // ~2.06 MB

  int S = 1;
  if      (ws_size >= used + 8 * perS) S = 8;
  else if (ws_size >= used + 4 * perS) S = 4;
  else if (ws_size >= used + 2 * perS) S = 2;
  u16*   y_part = (u16*)after;
  float* l_part = (float*)(y_part + (size_t)S * 128 * 128 * 64);
  const int tpb = 64 / S;

  proj_kernel<<<256, 256, 0, stream>>>(x, w_theta, b_theta, w_phi, b_phi,
                                       w_g, b_g, theta_t, phi_t, gbuf);
  attn_kernel<<<128 * S, 512, 0, stream>>>(theta_t, phi_t, gbuf, y_part, l_part, tpb);
  combine_kernel<<<512, 256, 0, stream>>>(y_part, l_part, x, w_out, b_out,
                                          bn_gamma, bn_beta, out, S);
}

// Round 6
// 69.505 us; speedup vs baseline: 1.0735x; 1.0284x over previous
//
#include <hip/hip_runtime.h>

typedef __attribute__((ext_vector_type(4))) float f32x4;
typedef __attribute__((ext_vector_type(8))) short bf16x8;
typedef unsigned short u16;
typedef unsigned int u32;

constexpr int NN = 4096;   // H*W

__device__ __forceinline__ u16 f2bf(float f){
  u32 u = __builtin_bit_cast(u32, f);
  u += 0x7FFFu + ((u >> 16) & 1u);          // round-to-nearest-even
  return (u16)(u >> 16);
}
__device__ __forceinline__ u32 cvtpk(float lo, float hi){
  u32 r;
  asm("v_cvt_pk_bf16_f32 %0, %1, %2" : "=v"(r) : "v"(lo), "v"(hi));
  return r;
}
__device__ __forceinline__ float fexp2(float x){
  float r;
  asm("v_exp_f32 %0, %1" : "=v"(r) : "v"(x));
  return r;
}
__device__ __forceinline__ void async16(void* lds, const void* g){
  __builtin_amdgcn_global_load_lds((const __attribute__((address_space(1))) void*)g,
                                   (__attribute__((address_space(3))) void*)lds,
                                   16, 0, 0);
}

// ---------------------------------------------------------------------------
// proj: weights staged in LDS (48 KB); xr register-resident.
// grid = 256 (4 batches x 64 n-chunks), 4 waves; wave w owns o in [16w,16w+16).
// theta gets *log2e folded in. theta_t/phi_t: [b][n][o] bf16; g: [b][o][n].
// ---------------------------------------------------------------------------
__global__ __launch_bounds__(256) void proj_kernel(
    const float* __restrict__ x,
    const float* __restrict__ wth, const float* __restrict__ bth,
    const float* __restrict__ wph, const float* __restrict__ bph,
    const float* __restrict__ wg,  const float* __restrict__ bg,
    u16* __restrict__ theta_t, u16* __restrict__ phi_t, u16* __restrict__ gbuf)
{
  __shared__ float Wsm[3 * 64 * 64];   // 48 KB
  __shared__ float Bsm[3 * 64];

  const int t = threadIdx.x;
#pragma unroll
  for (int i = 0; i < 4; ++i){
    ((float4*)Wsm)[i * 256 + t]            = ((const float4*)wth)[i * 256 + t];
    ((float4*)(Wsm + 4096))[i * 256 + t]   = ((const float4*)wph)[i * 256 + t];
    ((float4*)(Wsm + 8192))[i * 256 + t]   = ((const float4*)wg)[i * 256 + t];
  }
  if (t < 64){ Bsm[t] = bth[t]; Bsm[64 + t] = bph[t]; Bsm[128 + t] = bg[t]; }

  const int b = blockIdx.x >> 6;
  const int n = (blockIdx.x & 63) * 64 + (t & 63);
  const int w = __builtin_amdgcn_readfirstlane(t >> 6);

  const float* xb = x + ((size_t)b * 64) * NN + n;
  float xr[64];
#pragma unroll
  for (int c = 0; c < 64; ++c) xr[c] = xb[(size_t)c * NN];

  __syncthreads();

  for (int mat = 0; mat < 3; ++mat){
    const float* Wm = Wsm + mat * 4096 + (w * 16) * 64;
    float acc[16];
#pragma unroll
    for (int oo = 0; oo < 16; ++oo) acc[oo] = Bsm[mat * 64 + w * 16 + oo];
#pragma unroll
    for (int c4 = 0; c4 < 16; ++c4)
#pragma unroll
      for (int oo = 0; oo < 16; ++oo){
        const float4 wv = *(const float4*)&Wm[oo * 64 + c4 * 4];  // wave-broadcast
        acc[oo] = fmaf(wv.x, xr[4 * c4],     acc[oo]);
        acc[oo] = fmaf(wv.y, xr[4 * c4 + 1], acc[oo]);
        acc[oo] = fmaf(wv.z, xr[4 * c4 + 2], acc[oo]);
        acc[oo] = fmaf(wv.w, xr[4 * c4 + 3], acc[oo]);
      }

    if (mat == 0){
#pragma unroll
      for (int oo = 0; oo < 16; ++oo) acc[oo] *= 1.44269504088896340736f;
    }
    if (mat < 2){
      u32 pk[8];
#pragma unroll
      for (int h = 0; h < 8; ++h) pk[h] = cvtpk(acc[2 * h], acc[2 * h + 1]);
      u16* base = (mat == 0) ? theta_t : phi_t;
      u32* dst = (u32*)(base + ((size_t)(b * NN + n)) * 64 + w * 16);
      ((uint4*)dst)[0] = ((const uint4*)pk)[0];
      ((uint4*)dst)[1] = ((const uint4*)pk)[1];
    } else {
#pragma unroll
      for (int oo = 0; oo < 16; ++oo)
        gbuf[((size_t)(b * 64 + w * 16 + oo)) * NN + n] = f2bf(acc[oo]);
    }
  }
}

// ---------------------------------------------------------------------------
// attn v6: hoisted LDS addressing, l-via-MFMA(ones), static TPB full unroll,
// interleaved QK/SM/PV source order. BM=128 (8 waves x 16 rows), m-split S,
// XCD-aware bijective swizzle.
// ---------------------------------------------------------------------------
template<int TPB>
__global__ __launch_bounds__(512, 8) void attn_kernel(
    const u16* __restrict__ theta_t, const u16* __restrict__ phi_t,
    const u16* __restrict__ gbuf,
    u16* __restrict__ y_part, float* __restrict__ l_part)
{
  __shared__ u16 phi_sm[2][64 * 64];  // [m_loc][o], XOR-swizzled
  __shared__ u16 g_sm[2][64 * 64];    // [o][m_loc], XOR-swizzled

  const int j   = blockIdx.x;
  const int cpx = gridDim.x >> 3;
  const int lb  = (j & 7) * cpx + (j >> 3);   // bijective (grid % 8 == 0)

  const int ms  = lb >> 7;            // m-split index
  const int bt  = lb & 127;           // batch*32 + n-chunk
  const int b   = bt >> 5;
  const int n0  = (bt & 31) * 128;
  const int w   = __builtin_amdgcn_readfirstlane((int)threadIdx.x >> 6); // 0..7
  const int l   = threadIdx.x & 63;
  const int q   = l & 15;
  const int g   = l >> 4;
  const int swz = (q & 7) << 4;

  // tile-invariant LDS byte-offset bases (swz bits 4-6 disjoint from s*2048)
  const int baseK0 = ((g * 16) ^ swz) + q * 128;
  const int baseK1 = ((64 + g * 16) ^ swz) + q * 128;

  const u16* thb = theta_t + (size_t)b * NN * 64;

  bf16x8 tf[2];
#pragma unroll
  for (int ks = 0; ks < 2; ++ks)
    tf[ks] = *(const bf16x8*)(thb + (size_t)(n0 + w * 16 + q) * 64 + ks * 32 + g * 8);

  union { u32 u[4]; bf16x8 v; } onesu;
  onesu.u[0] = onesu.u[1] = onesu.u[2] = onesu.u[3] = 0x3F803F80u;
  const bf16x8 onesf = onesu.v;

  const int m0 = ms * TPB;
  const int r8 = l >> 3;
  const int c8 = l & 7;
  // running staging source pointers (per-lane), advanced per tile
  const u16* phi_src = phi_t + (size_t)b * NN * 64
                     + (size_t)(m0 * 64 + w * 8 + r8) * 64 + (c8 ^ r8) * 8;
  const u16* g_src   = gbuf + (size_t)b * 64 * NN
                     + (size_t)(w * 8 + r8) * NN + m0 * 64 + (c8 ^ r8) * 8;

  f32x4 yacc[4];
#pragma unroll
  for (int os = 0; os < 4; ++os) yacc[os] = (f32x4){0.f, 0.f, 0.f, 0.f};
  f32x4 lsum = (f32x4){0.f, 0.f, 0.f, 0.f};

  async16(&phi_sm[0][w * 512], phi_src);
  async16(&g_sm[0][w * 512],   g_src);
  phi_src += 4096; g_src += 64;

#pragma unroll
  for (int it = 0; it < TPB; ++it){
    const int cur = it & 1;
    if (it < TPB - 1){
      async16(&phi_sm[cur ^ 1][w * 512], phi_src);
      async16(&g_sm[cur ^ 1][w * 512],   g_src);
      phi_src += 4096; g_src += 64;
      asm volatile("s_waitcnt vmcnt(2)" ::: "memory");
    } else {
      asm volatile("s_waitcnt vmcnt(0)" ::: "memory");
    }
    __builtin_amdgcn_s_barrier();

    const char* phiB = (const char*)&phi_sm[cur][0];
    const char* gB   = (const char*)&g_sm[cur][0];

    // QK quadrant s: 2 MFMA, immediate offsets s*2048
#define QKS(dd, s)                                                              \
    {                                                                           \
      f32x4 a_ = (f32x4){0.f, 0.f, 0.f, 0.f};                                   \
      a_ = __builtin_amdgcn_mfma_f32_16x16x32_bf16(                             \
              *(const bf16x8*)(phiB + baseK0 + (s) * 2048), tf[0], a_, 0,0,0);  \
      a_ = __builtin_amdgcn_mfma_f32_16x16x32_bf16(                             \
              *(const bf16x8*)(phiB + baseK1 + (s) * 2048), tf[1], a_, 0,0,0);  \
      dd = a_;                                                                  \
    }
#define SMS(e0_, e1_, dd)                                                       \
    e0_ = cvtpk(fexp2(dd[0]), fexp2(dd[1]));                                    \
    e1_ = cvtpk(fexp2(dd[2]), fexp2(dd[3]));

    f32x4 d0, d1, d2, d3;
    u32 e00, e01, e10, e11, e20, e21, e30, e31;

    QKS(d0, 0) QKS(d1, 1)
    SMS(e00, e01, d0) SMS(e10, e11, d1)
    { // PV pair 0 (m rows 0..31) + l MFMA
      u32 a0 = e00, b0 = e10, a1 = e01, b1 = e11;
      asm("v_permlane32_swap_b32 %0, %1" : "+v"(a0), "+v"(b0));
      asm("v_permlane16_swap_b32 %0, %1" : "+v"(a0), "+v"(b0));
      asm("v_permlane32_swap_b32 %0, %1" : "+v"(a1), "+v"(b1));
      asm("v_permlane16_swap_b32 %0, %1" : "+v"(a1), "+v"(b1));
      union { u32 u[4]; bf16x8 v; } pw;
      pw.u[0] = a0; pw.u[1] = a1; pw.u[2] = b0; pw.u[3] = b1;
      lsum = __builtin_amdgcn_mfma_f32_16x16x32_bf16(pw.v, onesf, lsum, 0,0,0);
#pragma unroll
      for (int os = 0; os < 4; ++os)
        yacc[os] = __builtin_amdgcn_mfma_f32_16x16x32_bf16(
            pw.v, *(const bf16x8*)(gB + baseK0 + os * 2048), yacc[os], 0,0,0);
    }
    QKS(d2, 2) QKS(d3, 3)
    SMS(e20, e21, d2) SMS(e30, e31, d3)
    { // PV pair 1 (m rows 32..63) + l MFMA
      u32 a0 = e20, b0 = e30, a1 = e21, b1 = e31;
      asm("v_permlane32_swap_b32 %0, %1" : "+v"(a0), "+v"(b0));
      asm("v_permlane16_swap_b32 %0, %1" : "+v"(a0), "+v"(b0));
      asm("v_permlane32_swap_b32 %0, %1" : "+v"(a1), "+v"(b1));
      asm("v_permlane16_swap_b32 %0, %1" : "+v"(a1), "+v"(b1));
      union { u32 u[4]; bf16x8 v; } pw;
      pw.u[0] = a0; pw.u[1] = a1; pw.u[2] = b0; pw.u[3] = b1;
      lsum = __builtin_amdgcn_mfma_f32_16x16x32_bf16(pw.v, onesf, lsum, 0,0,0);
#pragma unroll
      for (int os = 0; os < 4; ++os)
        yacc[os] = __builtin_amdgcn_mfma_f32_16x16x32_bf16(
            pw.v, *(const bf16x8*)(gB + baseK1 + os * 2048), yacc[os], 0,0,0);
    }
#undef QKS
#undef SMS
    __builtin_amdgcn_s_barrier();
  }

  // partials: y_part[lb][n_loc(128)][o(64)] bf16
  u16* yp = y_part + (size_t)lb * (128 * 64);
#pragma unroll
  for (int os = 0; os < 4; ++os)
#pragma unroll
    for (int r = 0; r < 4; ++r)
      yp[(size_t)(w * 16 + g * 4 + r) * 64 + os * 16 + q] = f2bf(yacc[os][r]);

  // lsum[r] = l[n = w*16 + g*4 + r] (all q identical); lane q==0 stores 16B
  if (q == 0)
    *(f32x4*)(l_part + (size_t)lb * 128 + w * 16 + g * 4) = lsum;
}

// ---------------------------------------------------------------------------
// combine: 512 blocks x 32 rows. Sum S bf16 partials, normalize,
// w_out GEMM + bias/ReLU/BN + residual.
// ---------------------------------------------------------------------------
__global__ __launch_bounds__(256) void combine_kernel(
    const u16* __restrict__ y_part, const float* __restrict__ l_part,
    const float* __restrict__ x,
    const float* __restrict__ w_out, const float* __restrict__ b_out,
    const float* __restrict__ bn_gamma, const float* __restrict__ bn_beta,
    float* __restrict__ out, int S)
{
  __shared__ u16 y_sm[32 * 64];       // [row][o] bf16, swizzled
  __shared__ float inv_sm[32];

  const int cb      = blockIdx.x;           // 0..511
  const int b       = cb >> 7;
  const int nin     = (cb & 127) * 32;      // within-batch row base
  const int bt      = b * 32 + (nin >> 7);  // attn block id (0..127)
  const int rowbase = nin & 127;
  const int t       = threadIdx.x;
  const int row     = t >> 3;               // 0..31
  const int ch      = t & 7;                // 16B chunk (8 bf16)

  float s[8] = {0.f,0.f,0.f,0.f,0.f,0.f,0.f,0.f};
  for (int ms = 0; ms < S; ++ms){
    const u16* src = y_part + ((size_t)(ms * 128 + bt)) * (128 * 64)
                   + (size_t)(rowbase + row) * 64 + ch * 8;
    const uint4 v = *(const uint4*)src;
    const u32 ww[4] = {v.x, v.y, v.z, v.w};
#pragma unroll
    for (int i = 0; i < 4; ++i){
      s[2 * i]     += __builtin_bit_cast(float, ww[i] << 16);
      s[2 * i + 1] += __builtin_bit_cast(float, ww[i] & 0xFFFF0000u);
    }
  }
  if (t < 32){
    float ls = 0.f;
    for (int ms = 0; ms < S; ++ms)
      ls += l_part[((size_t)(ms * 128 + bt)) * 128 + rowbase + t];
    inv_sm[t] = 1.0f / ls;
  }
  __syncthreads();

  {
    const float inv = inv_sm[row];
    uint4 pk;
    pk.x = cvtpk(s[0] * inv, s[1] * inv);
    pk.y = cvtpk(s[2] * inv, s[3] * inv);
    pk.z = cvtpk(s[4] * inv, s[5] * inv);
    pk.w = cvtpk(s[6] * inv, s[7] * inv);
    *(uint4*)((char*)y_sm + ((row * 128 + ch * 16) ^ ((row & 7) << 4))) = pk;
  }
  __syncthreads();

  const int w   = __builtin_amdgcn_readfirstlane(t >> 6);
  const int l   = t & 63;
  const int q   = l & 15;
  const int gg  = l >> 4;
  const int swz = (q & 7) << 4;

  bf16x8 wf[2];
#pragma unroll
  for (int ks = 0; ks < 2; ++ks){
    bf16x8 v;
#pragma unroll
    for (int jj = 0; jj < 8; ++jj)
      v[jj] = (short)f2bf(w_out[(w * 16 + q) * 64 + ks * 32 + gg * 8 + jj]);
    wf[ks] = v;
  }
  f32x4 zacc[2];
  zacc[0] = (f32x4){0.f, 0.f, 0.f, 0.f};
  zacc[1] = (f32x4){0.f, 0.f, 0.f, 0.f};
#pragma unroll
  for (int ks = 0; ks < 2; ++ks)
#pragma unroll
    for (int ns = 0; ns < 2; ++ns){
      const int off = (((ns * 16 + q) * 128) + ks * 64 + gg * 16) ^ swz;
      const bf16x8 yf = *(const bf16x8*)((const char*)y_sm + off);
      zacc[ns] = __builtin_amdgcn_mfma_f32_16x16x32_bf16(wf[ks], yf, zacc[ns], 0, 0, 0);
    }

  float bo[4], sc_[4], bb_[4];
#pragma unroll
  for (int r = 0; r < 4; ++r){
    const int c = w * 16 + gg * 4 + r;
    bo[r]  = b_out[c];
    sc_[r] = bn_gamma[c] * 0.99999500003749969f;  // 1/sqrt(1+1e-5)
    bb_[r] = bn_beta[c];
  }
#pragma unroll
  for (int ns = 0; ns < 2; ++ns)
#pragma unroll
    for (int r = 0; r < 4; ++r){
      const int c  = w * 16 + gg * 4 + r;
      const int ng = nin + ns * 16 + q;
      const size_t idx = ((size_t)(b * 64 + c)) * NN + ng;
      float z = zacc[ns][r] + bo[r];
      z = fmaxf(z, 0.0f);
      z = z * sc_[r] + bb_[r];
      out[idx] = x[idx] + z;
    }
}

// ---------------------------------------------------------------------------
extern "C" void kernel_launch(void* const* d_in, const int* in_sizes, int n_in,
                              void* d_out, int out_size, void* d_ws, size_t ws_size,
                              hipStream_t stream)
{
  (void)in_sizes; (void)n_in; (void)out_size;
  const float* x        = (const float*)d_in[0];
  const float* w_theta  = (const float*)d_in[1];
  const float* b_theta  = (const float*)d_in[2];
  const float* w_phi    = (const float*)d_in[3];
  const float* b_phi    = (const float*)d_in[4];
  const float* w_g      = (const float*)d_in[5];
  const float* b_g      = (const float*)d_in[6];
  const float* w_out    = (const float*)d_in[7];
  const float* b_out    = (const float*)d_in[8];
  const float* bn_gamma = (const float*)d_in[9];
  const float* bn_beta  = (const float*)d_in[10];
  float* out = (float*)d_out;

  u16* theta_t = (u16*)d_ws;                       // 2 MB
  u16* phi_t   = theta_t + (size_t)4 * NN * 64;    // 2 MB
  u16* gbuf    = phi_t   + (size_t)4 * NN * 64;    // 2 MB
  char* after  = (char*)(gbuf + (size_t)4 * NN * 64);
  const size_t used = (size_t)(after - (char*)d_ws);
  const size_t perS = (size_t)128 * 128 * 64 * 2 + (size_t)128 * 128 * 4; // ~2.06 MB

  int S = 1;
  if      (ws_size >= used + 8 * perS) S = 8;
  else if (ws_size >= used + 4 * perS) S = 4;
  else if (ws_size >= used + 2 * perS) S = 2;
  u16*   y_part = (u16*)after;
  float* l_part = (float*)(y_part + (size_t)S * 128 * 128 * 64);

  proj_kernel<<<256, 256, 0, stream>>>(x, w_theta, b_theta, w_phi, b_phi,
                                       w_g, b_g, theta_t, phi_t, gbuf);
  if (S == 8)
    attn_kernel<8><<<1024, 512, 0, stream>>>(theta_t, phi_t, gbuf, y_part, l_part);
  else if (S == 4)
    attn_kernel<16><<<512, 512, 0, stream>>>(theta_t, phi_t, gbuf, y_part, l_part);
  else if (S == 2)
    attn_kernel<32><<<256, 512, 0, stream>>>(theta_t, phi_t, gbuf, y_part, l_part);
  else
    attn_kernel<64><<<128, 512, 0, stream>>>(theta_t, phi_t, gbuf, y_part, l_part);
  combine_kernel<<<512, 256, 0, stream>>>(y_part, l_part, x, w_out, b_out,
                                          bn_gamma, bn_beta, out, S);
}

// Round 7
// 67.786 us; speedup vs baseline: 1.1007x; 1.0254x over previous
//
#include <hip/hip_runtime.h>

typedef __attribute__((ext_vector_type(4))) float f32x4;
typedef __attribute__((ext_vector_type(16))) float f32x16;
typedef __attribute__((ext_vector_type(8))) short bf16x8;
typedef unsigned short u16;
typedef unsigned int u32;

constexpr int NN = 4096;   // H*W

__device__ __forceinline__ u16 f2bf(float f){
  u32 u = __builtin_bit_cast(u32, f);
  u += 0x7FFFu + ((u >> 16) & 1u);          // round-to-nearest-even
  return (u16)(u >> 16);
}
__device__ __forceinline__ u32 cvtpk(float lo, float hi){
  u32 r;
  asm("v_cvt_pk_bf16_f32 %0, %1, %2" : "=v"(r) : "v"(lo), "v"(hi));
  return r;
}
__device__ __forceinline__ float fexp2(float x){
  float r;
  asm("v_exp_f32 %0, %1" : "=v"(r) : "v"(x));
  return r;
}
__device__ __forceinline__ void async16(void* lds, const void* g){
  __builtin_amdgcn_global_load_lds((const __attribute__((address_space(1))) void*)g,
                                   (__attribute__((address_space(3))) void*)lds,
                                   16, 0, 0);
}

// ---------------------------------------------------------------------------
// proj: weights staged in LDS (48 KB); xr register-resident.
// grid = 256 (4 batches x 64 n-chunks), 4 waves; wave w owns o in [16w,16w+16).
// theta gets *log2e folded in. theta_t/phi_t: [b][n][o] bf16; g: [b][o][n].
// ---------------------------------------------------------------------------
__global__ __launch_bounds__(256) void proj_kernel(
    const float* __restrict__ x,
    const float* __restrict__ wth, const float* __restrict__ bth,
    const float* __restrict__ wph, const float* __restrict__ bph,
    const float* __restrict__ wg,  const float* __restrict__ bg,
    u16* __restrict__ theta_t, u16* __restrict__ phi_t, u16* __restrict__ gbuf)
{
  __shared__ float Wsm[3 * 64 * 64];   // 48 KB
  __shared__ float Bsm[3 * 64];

  const int t = threadIdx.x;
#pragma unroll
  for (int i = 0; i < 4; ++i){
    ((float4*)Wsm)[i * 256 + t]            = ((const float4*)wth)[i * 256 + t];
    ((float4*)(Wsm + 4096))[i * 256 + t]   = ((const float4*)wph)[i * 256 + t];
    ((float4*)(Wsm + 8192))[i * 256 + t]   = ((const float4*)wg)[i * 256 + t];
  }
  if (t < 64){ Bsm[t] = bth[t]; Bsm[64 + t] = bph[t]; Bsm[128 + t] = bg[t]; }

  const int b = blockIdx.x >> 6;
  const int n = (blockIdx.x & 63) * 64 + (t & 63);
  const int w = __builtin_amdgcn_readfirstlane(t >> 6);

  const float* xb = x + ((size_t)b * 64) * NN + n;
  float xr[64];
#pragma unroll
  for (int c = 0; c < 64; ++c) xr[c] = xb[(size_t)c * NN];

  __syncthreads();

  for (int mat = 0; mat < 3; ++mat){
    const float* Wm = Wsm + mat * 4096 + (w * 16) * 64;
    float acc[16];
#pragma unroll
    for (int oo = 0; oo < 16; ++oo) acc[oo] = Bsm[mat * 64 + w * 16 + oo];
#pragma unroll
    for (int c4 = 0; c4 < 16; ++c4)
#pragma unroll
      for (int oo = 0; oo < 16; ++oo){
        const float4 wv = *(const float4*)&Wm[oo * 64 + c4 * 4];  // wave-broadcast
        acc[oo] = fmaf(wv.x, xr[4 * c4],     acc[oo]);
        acc[oo] = fmaf(wv.y, xr[4 * c4 + 1], acc[oo]);
        acc[oo] = fmaf(wv.z, xr[4 * c4 + 2], acc[oo]);
        acc[oo] = fmaf(wv.w, xr[4 * c4 + 3], acc[oo]);
      }

    if (mat == 0){
#pragma unroll
      for (int oo = 0; oo < 16; ++oo) acc[oo] *= 1.44269504088896340736f;
    }
    if (mat < 2){
      u32 pk[8];
#pragma unroll
      for (int h = 0; h < 8; ++h) pk[h] = cvtpk(acc[2 * h], acc[2 * h + 1]);
      u16* base = (mat == 0) ? theta_t : phi_t;
      u32* dst = (u32*)(base + ((size_t)(b * NN + n)) * 64 + w * 16);
      ((uint4*)dst)[0] = ((const uint4*)pk)[0];
      ((uint4*)dst)[1] = ((const uint4*)pk)[1];
    } else {
#pragma unroll
      for (int oo = 0; oo < 16; ++oo)
        gbuf[((size_t)(b * 64 + w * 16 + oo)) * NN + n] = f2bf(acc[oo]);
    }
  }
}

// ---------------------------------------------------------------------------
// attn v7: 32x32x16 MFMA (2x FLOP per LDS operand byte). BM=256 (8 waves x
// 32 n-rows), m-split flash, fixed-base softmax (f32 l), single-permlane32
// P redistribution, XCD-aware bijective swizzle.
// grid = 64*S blocks x 512 threads.
// ---------------------------------------------------------------------------
template<int TPB>
__global__ __launch_bounds__(512, 4) void attn_kernel(
    const u16* __restrict__ theta_t, const u16* __restrict__ phi_t,
    const u16* __restrict__ gbuf,
    u16* __restrict__ y_part, float* __restrict__ l_part)
{
  __shared__ u16 phi_sm[2][64 * 64];  // [m_loc][o], XOR-swizzled
  __shared__ u16 g_sm[2][64 * 64];    // [o][m_loc], XOR-swizzled

  const int j   = blockIdx.x;
  const int cpx = gridDim.x >> 3;
  const int lb  = (j & 7) * cpx + (j >> 3);   // bijective (grid % 8 == 0)

  const int ms  = lb >> 6;            // m-split index
  const int pr  = lb & 63;            // batch*16 + n-chunk
  const int b   = pr >> 4;
  const int n0  = (pr & 15) * 256;

  const int tid = threadIdx.x;
  const int w   = __builtin_amdgcn_readfirstlane(tid >> 6); // 0..7
  const int l   = tid & 63;
  const int cc  = l & 31;             // 32-row lane field
  const int h   = l >> 5;             // half (k-group)
  const int sw  = (cc & 7) << 4;
  const int rb  = cc * 128;           // LDS row base (bytes)

  const u16* thb = theta_t + (size_t)b * NN * 64;

  // theta B-fragments: B[k=o][n], lane holds n = n0+w*32+cc, o = ks*16+h*8+j
  bf16x8 tf[4];
#pragma unroll
  for (int ks = 0; ks < 4; ++ks)
    tf[ks] = *(const bf16x8*)(thb + (size_t)(n0 + w * 32 + cc) * 64 + ks * 16 + h * 8);

  const int m0 = ms * TPB;
  const int r8 = l >> 3;
  const int c8 = l & 7;
  const u16* phi_src = phi_t + (size_t)b * NN * 64
                     + (size_t)(m0 * 64 + w * 8 + r8) * 64 + (c8 ^ r8) * 8;
  const u16* g_src   = gbuf + (size_t)b * 64 * NN
                     + (size_t)(w * 8 + r8) * NN + m0 * 64 + (c8 ^ r8) * 8;

  f32x16 yacc0, yacc1;
#pragma unroll
  for (int i = 0; i < 16; ++i){ yacc0[i] = 0.f; yacc1[i] = 0.f; }
  float lacc = 0.f;

  async16(&phi_sm[0][w * 512], phi_src);
  async16(&g_sm[0][w * 512],   g_src);
  phi_src += 4096; g_src += 64;

#pragma unroll 2
  for (int it = 0; it < TPB; ++it){
    const int cur = it & 1;
    if (it < TPB - 1){
      async16(&phi_sm[cur ^ 1][w * 512], phi_src);
      async16(&g_sm[cur ^ 1][w * 512],   g_src);
      phi_src += 4096; g_src += 64;
      asm volatile("s_waitcnt vmcnt(2)" ::: "memory");
    } else {
      asm volatile("s_waitcnt vmcnt(0)" ::: "memory");
    }
    __builtin_amdgcn_s_barrier();

    const char* phiB = (const char*)&phi_sm[cur][0];
    const char* gB   = (const char*)&g_sm[cur][0];

#pragma unroll
    for (int t = 0; t < 2; ++t){
      // QK^T m-tile t: P[m = 32t + (reg&3)+8*(reg>>2)+4h][n = cc]
      __builtin_amdgcn_s_setprio(1);
      f32x16 p;
#pragma unroll
      for (int i = 0; i < 16; ++i) p[i] = 0.f;
#pragma unroll
      for (int ks = 0; ks < 4; ++ks)
        p = __builtin_amdgcn_mfma_f32_32x32x16_bf16(
              *(const bf16x8*)(phiB + t * 4096 + rb + ((ks * 32 + h * 16) ^ sw)),
              tf[ks], p, 0, 0, 0);
      __builtin_amdgcn_s_setprio(0);

      // fixed-base softmax (f32 l), pack to bf16 words w[rq][p]
      u32 wpk[4][2];
#pragma unroll
      for (int rq = 0; rq < 4; ++rq){
        const float e0 = fexp2(p[4 * rq + 0]), e1 = fexp2(p[4 * rq + 1]);
        const float e2 = fexp2(p[4 * rq + 2]), e3 = fexp2(p[4 * rq + 3]);
        lacc += (e0 + e1) + (e2 + e3);
        wpk[rq][0] = cvtpk(e0, e1);
        wpk[rq][1] = cvtpk(e2, e3);
      }

      // PV: one permlane32_swap per word-pair builds A[n][m] fragments
      __builtin_amdgcn_s_setprio(1);
#pragma unroll
      for (int par = 0; par < 2; ++par){
        u32 A0 = wpk[2 * par][0],     A1 = wpk[2 * par][1];
        u32 B0 = wpk[2 * par + 1][0], B1 = wpk[2 * par + 1][1];
        asm("v_permlane32_swap_b32 %0, %1" : "+v"(A0), "+v"(B0));
        asm("v_permlane32_swap_b32 %0, %1" : "+v"(A1), "+v"(B1));
        union { u32 u[4]; bf16x8 v; } pw;
        pw.u[0] = A0; pw.u[1] = A1; pw.u[2] = B0; pw.u[3] = B1;
        const int s   = t * 2 + par;
        const int gof = (s * 32 + h * 16) ^ sw;
        yacc0 = __builtin_amdgcn_mfma_f32_32x32x16_bf16(
                  pw.v, *(const bf16x8*)(gB + rb + gof), yacc0, 0, 0, 0);
        yacc1 = __builtin_amdgcn_mfma_f32_32x32x16_bf16(
                  pw.v, *(const bf16x8*)(gB + 4096 + rb + gof), yacc1, 0, 0, 0);
      }
      __builtin_amdgcn_s_setprio(0);
    }
    __builtin_amdgcn_s_barrier();
  }

  // cross-half l combine (f32): ltot = own + partner
  {
    u32 la = __builtin_bit_cast(u32, lacc), lb2 = la;
    asm("v_permlane32_swap_b32 %0, %1" : "+v"(la), "+v"(lb2));
    const float ltot = __builtin_bit_cast(float, la) + __builtin_bit_cast(float, lb2);
    if (l < 32)
      l_part[(size_t)(ms * 4 + b) * NN + n0 + w * 32 + cc] = ltot;
  }

  // partials: y_part[ms*4+b][n][o] bf16; lane owns col o = 32*ot + cc
  u16* yp = y_part + ((size_t)(ms * 4 + b) * NN + n0 + w * 32) * 64 + cc;
#pragma unroll
  for (int r = 0; r < 16; ++r){
    const int nl = (r & 3) + 8 * (r >> 2) + 4 * h;
    yp[(size_t)nl * 64]      = f2bf(yacc0[r]);
    yp[(size_t)nl * 64 + 32] = f2bf(yacc1[r]);
  }
}

// ---------------------------------------------------------------------------
// combine: 512 blocks x 32 rows. Sum S bf16 partials, normalize,
// w_out GEMM + bias/ReLU/BN + residual.
// ---------------------------------------------------------------------------
__global__ __launch_bounds__(256) void combine_kernel(
    const u16* __restrict__ y_part, const float* __restrict__ l_part,
    const float* __restrict__ x,
    const float* __restrict__ w_out, const float* __restrict__ b_out,
    const float* __restrict__ bn_gamma, const float* __restrict__ bn_beta,
    float* __restrict__ out, int S)
{
  __shared__ u16 y_sm[32 * 64];       // [row][o] bf16, swizzled
  __shared__ float inv_sm[32];

  const int cb   = blockIdx.x;            // 0..511
  const int b    = cb >> 7;
  const int nin  = (cb & 127) * 32;       // row base within batch
  const int t    = threadIdx.x;
  const int row  = t >> 3;                // 0..31
  const int ch   = t & 7;                 // 16B chunk (8 bf16)

  float s[8] = {0.f,0.f,0.f,0.f,0.f,0.f,0.f,0.f};
  for (int ms = 0; ms < S; ++ms){
    const u16* src = y_part + ((size_t)(ms * 4 + b) * NN + nin + row) * 64 + ch * 8;
    const uint4 v = *(const uint4*)src;
    const u32 ww[4] = {v.x, v.y, v.z, v.w};
#pragma unroll
    for (int i = 0; i < 4; ++i){
      s[2 * i]     += __builtin_bit_cast(float, ww[i] << 16);
      s[2 * i + 1] += __builtin_bit_cast(float, ww[i] & 0xFFFF0000u);
    }
  }
  if (t < 32){
    float ls = 0.f;
    for (int ms = 0; ms < S; ++ms)
      ls += l_part[(size_t)(ms * 4 + b) * NN + nin + t];
    inv_sm[t] = 1.0f / ls;
  }
  __syncthreads();

  {
    const float inv = inv_sm[row];
    uint4 pk;
    pk.x = cvtpk(s[0] * inv, s[1] * inv);
    pk.y = cvtpk(s[2] * inv, s[3] * inv);
    pk.z = cvtpk(s[4] * inv, s[5] * inv);
    pk.w = cvtpk(s[6] * inv, s[7] * inv);
    *(uint4*)((char*)y_sm + ((row * 128 + ch * 16) ^ ((row & 7) << 4))) = pk;
  }
  __syncthreads();

  const int w   = __builtin_amdgcn_readfirstlane(t >> 6);
  const int l   = t & 63;
  const int q   = l & 15;
  const int gg  = l >> 4;
  const int swz = (q & 7) << 4;

  bf16x8 wf[2];
#pragma unroll
  for (int ks = 0; ks < 2; ++ks){
    bf16x8 v;
#pragma unroll
    for (int jj = 0; jj < 8; ++jj)
      v[jj] = (short)f2bf(w_out[(w * 16 + q) * 64 + ks * 32 + gg * 8 + jj]);
    wf[ks] = v;
  }
  f32x4 zacc[2];
  zacc[0] = (f32x4){0.f, 0.f, 0.f, 0.f};
  zacc[1] = (f32x4){0.f, 0.f, 0.f, 0.f};
#pragma unroll
  for (int ks = 0; ks < 2; ++ks)
#pragma unroll
    for (int ns = 0; ns < 2; ++ns){
      const int off = (((ns * 16 + q) * 128) + ks * 64 + gg * 16) ^ swz;
      const bf16x8 yf = *(const bf16x8*)((const char*)y_sm + off);
      zacc[ns] = __builtin_amdgcn_mfma_f32_16x16x32_bf16(wf[ks], yf, zacc[ns], 0, 0, 0);
    }

  float bo[4], sc_[4], bb_[4];
#pragma unroll
  for (int r = 0; r < 4; ++r){
    const int c = w * 16 + gg * 4 + r;
    bo[r]  = b_out[c];
    sc_[r] = bn_gamma[c] * 0.99999500003749969f;  // 1/sqrt(1+1e-5)
    bb_[r] = bn_beta[c];
  }
#pragma unroll
  for (int ns = 0; ns < 2; ++ns)
#pragma unroll
    for (int r = 0; r < 4; ++r){
      const int c  = w * 16 + gg * 4 + r;
      const int ng = nin + ns * 16 + q;
      const size_t idx = ((size_t)(b * 64 + c)) * NN + ng;
      float z = zacc[ns][r] + bo[r];
      z = fmaxf(z, 0.0f);
      z = z * sc_[r] + bb_[r];
      out[idx] = x[idx] + z;
    }
}

// ---------------------------------------------------------------------------
extern "C" void kernel_launch(void* const* d_in, const int* in_sizes, int n_in,
                              void* d_out, int out_size, void* d_ws, size_t ws_size,
                              hipStream_t stream)
{
  (void)in_sizes; (void)n_in; (void)out_size;
  const float* x        = (const float*)d_in[0];
  const float* w_theta  = (const float*)d_in[1];
  const float* b_theta  = (const float*)d_in[2];
  const float* w_phi    = (const float*)d_in[3];
  const float* b_phi    = (const float*)d_in[4];
  const float* w_g      = (const float*)d_in[5];
  const float* b_g      = (const float*)d_in[6];
  const float* w_out    = (const float*)d_in[7];
  const float* b_out    = (const float*)d_in[8];
  const float* bn_gamma = (const float*)d_in[9];
  const float* bn_beta  = (const float*)d_in[10];
  float* out = (float*)d_out;

  u16* theta_t = (u16*)d_ws;                       // 2 MB
  u16* phi_t   = theta_t + (size_t)4 * NN * 64;    // 2 MB
  u16* gbuf    = phi_t   + (size_t)4 * NN * 64;    // 2 MB
  char* after  = (char*)(gbuf + (size_t)4 * NN * 64);
  const size_t used = (size_t)(after - (char*)d_ws);
  const size_t perS = (size_t)4 * NN * 64 * 2 + (size_t)4 * NN * 4; // ~2.16 MB

  int S = 1;
  if      (ws_size >= used + 8 * perS) S = 8;
  else if (ws_size >= used + 4 * perS) S = 4;
  else if (ws_size >= used + 2 * perS) S = 2;
  u16*   y_part = (u16*)after;
  float* l_part = (float*)(y_part + (size_t)S * 4 * NN * 64);

  proj_kernel<<<256, 256, 0, stream>>>(x, w_theta, b_theta, w_phi, b_phi,
                                       w_g, b_g, theta_t, phi_t, gbuf);
  if (S == 8)
    attn_kernel<8><<<512, 512, 0, stream>>>(theta_t, phi_t, gbuf, y_part, l_part);
  else if (S == 4)
    attn_kernel<16><<<256, 512, 0, stream>>>(theta_t, phi_t, gbuf, y_part, l_part);
  else if (S == 2)
    attn_kernel<32><<<128, 512, 0, stream>>>(theta_t, phi_t, gbuf, y_part, l_part);
  else
    attn_kernel<64><<<64, 512, 0, stream>>>(theta_t, phi_t, gbuf, y_part, l_part);
  combine_kernel<<<512, 256, 0, stream>>>(y_part, l_part, x, w_out, b_out,
                                          bn_gamma, bn_beta, out, S);
}